// Round 9
// baseline (765.977 us; speedup 1.0000x reference)
//
#include <hip/hip_runtime.h>
#include <hip/hip_bf16.h>

#define D 64
#define BN 64   // nodes per bin

typedef float f32x4 __attribute__((ext_vector_type(4)));

// ---- kernel 0: zero counts (int4) ----
__global__ void zero_kernel(int4* __restrict__ p, int n4) {
    int i = blockIdx.x * blockDim.x + threadIdx.x;
    if (i < n4) p[i] = make_int4(0, 0, 0, 0);
}

// ---- kernel 1: histogram counts[dst[e]]++ (int4 reads) ----
__global__ void count_kernel(const int4* __restrict__ dst4, int* __restrict__ counts, int E4) {
    int i = blockIdx.x * blockDim.x + threadIdx.x;
    if (i < E4) {
        int4 d = dst4[i];
        atomicAdd(&counts[d.x], 1);
        atomicAdd(&counts[d.y], 1);
        atomicAdd(&counts[d.z], 1);
        atomicAdd(&counts[d.w], 1);
    }
}

// ---- kernel 2: per-bin edge totals (bin = 64 nodes; 4 bins per 256-thr block) ----
__global__ void binsum_kernel(const int* __restrict__ counts, int* __restrict__ bsums,
                              int N, int nbins) {
    int t = threadIdx.x;
    int lane = t & 63, w = t >> 6;
    int bin = blockIdx.x * 4 + w;
    int i = bin * BN + lane;
    int v = (bin < nbins && i < N) ? counts[i] : 0;
    #pragma unroll
    for (int o = 1; o < 64; o <<= 1) v += __shfl_xor(v, o);
    if (lane == 0 && bin < nbins) bsums[bin] = v;
}

// ---- kernel 3: single-block exclusive scan of bin sums (nbins<=1024) + Wc/bc combine ----
__global__ void binscan_kernel(const int* __restrict__ bsums, int* __restrict__ boffs,
                               int* __restrict__ bincur, int nbins,
                               const float* __restrict__ Wp, const float* __restrict__ Wu,
                               const float* __restrict__ bp,
                               float* __restrict__ Wc, float* __restrict__ bc) {
    __shared__ int wsum[16];
    __shared__ float wu[D * D];
    __shared__ float wp[D * D];
    int t = threadIdx.x;
    for (int i = t; i < D * D; i += 1024) { wu[i] = Wu[i]; wp[i] = Wp[i]; }

    int wave = t >> 6, lane = t & 63;
    int v = (t < nbins) ? bsums[t] : 0;
    int s = v;
    #pragma unroll
    for (int off = 1; off < 64; off <<= 1) {
        int x = __shfl_up(s, off);
        if (lane >= off) s += x;
    }
    if (lane == 63) wsum[wave] = s;
    __syncthreads();
    int wbase = 0, total = 0;
    #pragma unroll
    for (int w = 0; w < 16; ++w) {
        int x = wsum[w];
        total += x;
        if (w < wave) wbase += x;
    }
    if (t < nbins) {
        int excl = s - v + wbase;
        boffs[t] = excl;
        bincur[t] = excl;
    }
    if (t == 0) boffs[nbins] = total;   // == E

    // fused combine: Wc = Wp @ Wu, bc = bp @ Wu
    for (int idx = t; idx < D * D; idx += 1024) {
        int d = idx >> 6, j = idx & 63;
        float acc = 0.f;
        #pragma unroll
        for (int k = 0; k < D; ++k) acc = fmaf(wp[d * D + k], wu[k * D + j], acc);
        Wc[idx] = acc;
    }
    if (t < D) {
        float acc = 0.f;
        #pragma unroll
        for (int k = 0; k < D; ++k) acc = fmaf(bp[k], wu[k * D + t], acc);
        bc[t] = acc;
    }
}

// ---- kernel 4 (pass 1): stream attrs linearly, convert to bf16, append row to its bin ----
// Wave = 4 edges x 16 lanes. Reads 1KB contiguous per instr; writes 128B rows bin-locally.
__global__ __launch_bounds__(256) void scatter_bin_kernel(
        const f32x4* __restrict__ attrs4, const int* __restrict__ dst,
        int* __restrict__ bincur, ushort4* __restrict__ ebin,
        int* __restrict__ idbin, int E) {
    int lane = threadIdx.x & 63;
    int s = lane >> 4;      // edge slot 0..3
    int c = lane & 15;      // 16B chunk of f32 row (4 dims)
    int wid = (blockIdx.x * 256 + threadIdx.x) >> 6;
    int nw = (gridDim.x * 256) >> 6;
    for (int e0 = wid * 4; e0 < E; e0 += nw * 4) {
        int e = e0 + s;                       // E % 4 == 0 -> always valid
        f32x4 a = attrs4[(size_t)e * 16 + c];
        int pos = 0, node = 0;
        if (c == 0) {
            node = dst[e];
            pos = atomicAdd(&bincur[node >> 6], 1);
        }
        pos = __shfl(pos, s << 4);
        unsigned u0 = __float_as_uint(a.x), u1 = __float_as_uint(a.y);
        unsigned u2 = __float_as_uint(a.z), u3 = __float_as_uint(a.w);
        u0 = (u0 + 0x7fffu + ((u0 >> 16) & 1u)) >> 16;
        u1 = (u1 + 0x7fffu + ((u1 >> 16) & 1u)) >> 16;
        u2 = (u2 + 0x7fffu + ((u2 >> 16) & 1u)) >> 16;
        u3 = (u3 + 0x7fffu + ((u3 >> 16) & 1u)) >> 16;
        ushort4 pk = make_ushort4((unsigned short)u0, (unsigned short)u1,
                                  (unsigned short)u2, (unsigned short)u3);
        ebin[(size_t)pos * 16 + c] = pk;      // row = 16 x 8B = 128B
        if (c == 0) idbin[pos] = node;
    }
}

// ---- kernel 5 (pass 2): per-bin streaming reduce into LDS + mean + fused matmul ----
// Wave = 8 edges x 8 lanes (16B bf16 chunk = 8 dims each).
__global__ __launch_bounds__(256) void bin_reduce_kernel(
        const uint4* __restrict__ ebin, const int* __restrict__ idbin,
        const int* __restrict__ boffs, const int* __restrict__ counts,
        const float* __restrict__ Wc, const float* __restrict__ bcv,
        const float* __restrict__ ub, float* __restrict__ out, int N) {
    __shared__ float accum[BN * D];   // 16KB
    __shared__ float wlds[D * D];     // 16KB
    __shared__ float blds[D];
    __shared__ float ulds[D];
    int t = threadIdx.x;
    int b = blockIdx.x;
    for (int i = t; i < BN * D; i += 256) accum[i] = 0.f;
    for (int i = t; i < D * D; i += 256) wlds[i] = Wc[i];
    if (t < D) { blds[t] = bcv[t]; ulds[t] = ub[t]; }
    __syncthreads();

    int lo = boffs[b], hi = boffs[b + 1];
    int lane = t & 63, w = t >> 6;
    int s = lane >> 3;    // edge slot 0..7
    int c = lane & 7;     // 16B chunk (8 bf16 dims)
    int base0 = b * BN;

    for (int p0 = lo + w * 8; p0 < hi; p0 += 32) {
        int p = p0 + s;
        bool valid = p < hi;
        int node = 0;
        if (c == 0 && valid) node = idbin[p];
        node = __shfl(node, lane & 56);       // broadcast from group leader
        uint4 rv = make_uint4(0u, 0u, 0u, 0u);
        if (valid) rv = ebin[(size_t)p * 8 + c];
        if (valid) {
            int nl = node - base0;
            float f[8];
            f[0] = __uint_as_float(rv.x << 16); f[1] = __uint_as_float(rv.x & 0xffff0000u);
            f[2] = __uint_as_float(rv.y << 16); f[3] = __uint_as_float(rv.y & 0xffff0000u);
            f[4] = __uint_as_float(rv.z << 16); f[5] = __uint_as_float(rv.z & 0xffff0000u);
            f[6] = __uint_as_float(rv.w << 16); f[7] = __uint_as_float(rv.w & 0xffff0000u);
            int abase = nl * D + c * 8;
            #pragma unroll
            for (int k = 0; k < 8; ++k) {
                int kk = (k + s) & 7;         // bank stagger: 64 distinct dims per step
                atomicAdd(&accum[abase + kk], f[kk]);
            }
        }
    }
    __syncthreads();

    // epilogue: 16 nodes per wave
    for (int nl = w * 16; nl < w * 16 + 16; ++nl) {
        int n = base0 + nl;
        if (n >= N) break;
        int cnt = counts[n];
        float inv = (cnt > 0) ? 1.f / (float)cnt : 0.f;
        float mean = accum[nl * D + lane] * inv;
        float acc = ulds[lane] + ((cnt > 0) ? blds[lane] : 0.f);
        #pragma unroll
        for (int d = 0; d < D; ++d) {
            float mv = __shfl(mean, d);
            acc = fmaf(mv, wlds[d * D + lane], acc);
        }
        out[(size_t)n * D + lane] = acc;
    }
}

extern "C" void kernel_launch(void* const* d_in, const int* in_sizes, int n_in,
                              void* d_out, int out_size, void* d_ws, size_t ws_size,
                              hipStream_t stream) {
    const float* edge_attrs = (const float*)d_in[0];
    const float* proj_W     = (const float*)d_in[1];
    const float* proj_b     = (const float*)d_in[2];
    const float* upd_W      = (const float*)d_in[3];
    const float* upd_b      = (const float*)d_in[4];
    const int*   dst        = (const int*)d_in[5];

    const int E = in_sizes[0] / D;
    const int N = out_size / D;
    const int nbins = (N + BN - 1) / BN;     // 782 for N=50000
    const int E4 = E / 4;
    const int N4 = N / 4;

    // ws layout
    int*   counts  = (int*)d_ws;             // N
    int*   bsums   = counts + N;             // nbins
    int*   boffs   = bsums + nbins;          // nbins+1
    int*   bincur  = boffs + nbins + 1;      // nbins
    float* Wc      = (float*)(bincur + nbins);
    float* bc      = Wc + D * D;
    int*   idbin   = (int*)(bc + D);         // E
    size_t ebin_off = (((size_t)(idbin + E) - (size_t)d_ws) + 255) & ~(size_t)255;
    ushort4* ebin   = (ushort4*)((char*)d_ws + ebin_off);   // E rows x 128B, bin-grouped

    zero_kernel<<<(N4 + 255) / 256, 256, 0, stream>>>((int4*)counts, N4);
    count_kernel<<<(E4 + 255) / 256, 256, 0, stream>>>((const int4*)dst, counts, E4);
    binsum_kernel<<<(nbins + 3) / 4, 256, 0, stream>>>(counts, bsums, N, nbins);
    binscan_kernel<<<1, 1024, 0, stream>>>(bsums, boffs, bincur, nbins,
                                           proj_W, upd_W, proj_b, Wc, bc);
    scatter_bin_kernel<<<2048, 256, 0, stream>>>((const f32x4*)edge_attrs, dst,
                                                 bincur, ebin, idbin, E);
    bin_reduce_kernel<<<nbins, 256, 0, stream>>>((const uint4*)ebin, idbin, boffs,
                                                 counts, Wc, bc, upd_b,
                                                 (float*)d_out, N);
}

// Round 10
// 173.991 us; speedup vs baseline: 4.4024x; 4.4024x over previous
//
#include <hip/hip_runtime.h>
#include <hip/hip_bf16.h>

#define D 64

typedef float f32x4 __attribute__((ext_vector_type(4)));

// ---- kernel 0: zero counts (int4, includes padding) ----
__global__ void zero_kernel(int4* __restrict__ p, int n4) {
    int i = blockIdx.x * blockDim.x + threadIdx.x;
    if (i < n4) p[i] = make_int4(0, 0, 0, 0);
}

// ---- kernel 1: histogram counts[dst[e]]++ (int4 reads) ----
__global__ void count_kernel(const int4* __restrict__ dst4, int* __restrict__ counts, int E4) {
    int i = blockIdx.x * blockDim.x + threadIdx.x;
    if (i < E4) {
        int4 d = dst4[i];
        atomicAdd(&counts[d.x], 1);
        atomicAdd(&counts[d.y], 1);
        atomicAdd(&counts[d.z], 1);
        atomicAdd(&counts[d.w], 1);
    }
}

// ---- kernel 2: single-block exclusive scan (int4, shfl, 2 barriers/chunk) + Wc/bc combine ----
__global__ void scan4_kernel(const int4* __restrict__ counts4, int N4, int N,
                             int4* __restrict__ offsets4, int4* __restrict__ cursor4,
                             int* __restrict__ offsets,
                             const float* __restrict__ Wp, const float* __restrict__ Wu,
                             const float* __restrict__ bp,
                             float* __restrict__ Wc, float* __restrict__ bc) {
    __shared__ int wsum[16];
    __shared__ float wu[D * D];
    __shared__ float wp[D * D];
    int t = threadIdx.x;
    // stage weights early; loads overlap the scan
    for (int i = t; i < D * D; i += 1024) { wu[i] = Wu[i]; wp[i] = Wp[i]; }

    int wave = t >> 6, lane = t & 63;
    int carry = 0;
    int nchunk = (N4 + 1023) / 1024;
    for (int ch = 0; ch < nchunk; ++ch) {
        int i = ch * 1024 + t;
        int4 v = make_int4(0, 0, 0, 0);
        if (i < N4) v = counts4[i];
        int vs = v.x + v.y + v.z + v.w;
        int s = vs;
        #pragma unroll
        for (int off = 1; off < 64; off <<= 1) {
            int x = __shfl_up(s, off);
            if (lane >= off) s += x;
        }
        if (lane == 63) wsum[wave] = s;
        __syncthreads();
        int wbase = 0, total = 0;
        #pragma unroll
        for (int w = 0; w < 16; ++w) {
            int x = wsum[w];
            total += x;
            if (w < wave) wbase += x;
        }
        if (i < N4) {
            int e0 = s - vs + wbase + carry;   // exclusive before v.x
            int4 o;
            o.x = e0;
            o.y = e0 + v.x;
            o.z = o.y + v.y;
            o.w = o.z + v.z;
            offsets4[i] = o;
            cursor4[i] = o;
        }
        carry += total;
        __syncthreads();   // protect wsum before next chunk
    }
    if (t == 0) offsets[N] = carry;   // == E (safe for N%4==0; else redundant)

    __syncthreads();
    // ---- fused combine: Wc = Wp @ Wu, bc = bp @ Wu (operands in LDS) ----
    for (int idx = t; idx < D * D; idx += 1024) {
        int d = idx >> 6, j = idx & 63;
        float acc = 0.f;
        #pragma unroll
        for (int k = 0; k < D; ++k) acc = fmaf(wp[d * D + k], wu[k * D + j], acc);
        Wc[idx] = acc;
    }
    if (t < D) {
        float acc = 0.f;
        #pragma unroll
        for (int k = 0; k < D; ++k) acc = fmaf(bp[k], wu[k * D + t], acc);
        bc[t] = acc;
    }
}

// ---- kernel 3: scatter edge ids into CSR slots (int4 reads) ----
__global__ void fill_kernel(const int4* __restrict__ dst4, int* __restrict__ cursor,
                            int* __restrict__ csr, int E4) {
    int i = blockIdx.x * blockDim.x + threadIdx.x;
    if (i < E4) {
        int4 d = dst4[i];
        int e = i * 4;
        csr[atomicAdd(&cursor[d.x], 1)] = e + 0;
        csr[atomicAdd(&cursor[d.y], 1)] = e + 1;
        csr[atomicAdd(&cursor[d.z], 1)] = e + 2;
        csr[atomicAdd(&cursor[d.w], 1)] = e + 3;
    }
}

// ---- kernel 4: per-node gather (float4, 8 edges in flight) + mean + fused matmul ----
__global__ __launch_bounds__(256) void node_kernel(
        const float4* __restrict__ attrs4, const int* __restrict__ csr,
        const int* __restrict__ offsets,
        const float* __restrict__ Wc, const float* __restrict__ bc,
        const float* __restrict__ ub, float* __restrict__ out, int N) {
    __shared__ float wlds[D * D];
    __shared__ float blds[D];
    __shared__ float ulds[D];
    __shared__ int soff[5];
    int t = threadIdx.x;
    int nbase = blockIdx.x * 4;
    if (t < 5) {
        int nn = nbase + t;
        soff[t] = offsets[(nn <= N) ? nn : N];
    }
    #pragma unroll
    for (int i = t; i < D * D; i += 256) wlds[i] = Wc[i];
    if (t < D) { blds[t] = bc[t]; ulds[t] = ub[t]; }
    __syncthreads();

    int wave = t >> 6, lane = t & 63;
    int n = nbase + wave;
    if (n >= N) return;

    int off = soff[wave];
    int cnt = soff[wave + 1] - off;

    int g = lane >> 4;      // edge subgroup 0..3
    int q = lane & 15;      // quarter-row (float4 index within row)

    float4 acc0 = make_float4(0.f, 0.f, 0.f, 0.f);
    float4 acc1 = make_float4(0.f, 0.f, 0.f, 0.f);
    for (int base = 0; base < cnt; base += 64) {
        int m = cnt - base; if (m > 64) m = 64;
        // cooperative coalesced index load: one 256B load covers up to 64 edges
        int idxv = (lane < m) ? csr[off + base + lane] : 0;
        int jj = 0;
        for (; jj + 8 <= m; jj += 8) {
            int e0 = __shfl(idxv, jj + g);
            int e1 = __shfl(idxv, jj + 4 + g);
            float4 a0 = attrs4[(size_t)e0 * 16 + q];
            float4 a1 = attrs4[(size_t)e1 * 16 + q];
            acc0.x += a0.x; acc0.y += a0.y; acc0.z += a0.z; acc0.w += a0.w;
            acc1.x += a1.x; acc1.y += a1.y; acc1.z += a1.z; acc1.w += a1.w;
        }
        for (; jj < m; jj += 4) {
            int sel = jj + g;
            int e = __shfl(idxv, sel);
            if (sel < m) {
                float4 a = attrs4[(size_t)e * 16 + q];
                acc0.x += a.x; acc0.y += a.y; acc0.z += a.z; acc0.w += a.w;
            }
        }
    }
    float4 acc = make_float4(acc0.x + acc1.x, acc0.y + acc1.y,
                             acc0.z + acc1.z, acc0.w + acc1.w);
    // reduce across the 4 edge subgroups (lanes differing in bits 4,5)
    acc.x += __shfl_xor(acc.x, 16); acc.y += __shfl_xor(acc.y, 16);
    acc.z += __shfl_xor(acc.z, 16); acc.w += __shfl_xor(acc.w, 16);
    acc.x += __shfl_xor(acc.x, 32); acc.y += __shfl_xor(acc.y, 32);
    acc.z += __shfl_xor(acc.z, 32); acc.w += __shfl_xor(acc.w, 32);

    float inv = (cnt > 0) ? 1.f / (float)cnt : 0.f;
    float marr[4] = { acc.x * inv, acc.y * inv, acc.z * inv, acc.w * inv };
    // lane q holds mean[4q..4q+3]

    float accO = ulds[lane] + ((cnt > 0) ? blds[lane] : 0.f);
    #pragma unroll
    for (int d = 0; d < D; ++d) {
        float mv = __shfl(marr[d & 3], d >> 2);
        accO = fmaf(mv, wlds[d * D + lane], accO);
    }
    out[(size_t)n * D + lane] = accO;
}

extern "C" void kernel_launch(void* const* d_in, const int* in_sizes, int n_in,
                              void* d_out, int out_size, void* d_ws, size_t ws_size,
                              hipStream_t stream) {
    const float* edge_attrs = (const float*)d_in[0];
    const float* proj_W     = (const float*)d_in[1];
    const float* proj_b     = (const float*)d_in[2];
    const float* upd_W      = (const float*)d_in[3];
    const float* upd_b      = (const float*)d_in[4];
    const int*   dst        = (const int*)d_in[5];

    const int E = in_sizes[0] / D;
    const int N = out_size / D;
    const int E4 = E / 4;                    // E=800000 divisible by 4
    const int N4 = (N + 3) / 4;              // int4 count for N=50000 -> 12500
    const int Npad = N4 * 4 + 4;             // padded sizes keep int4 alignment

    // ws layout (base 256B-aligned by harness; all chunks multiples of 16B)
    int*   counts  = (int*)d_ws;             // Npad
    int*   offsets = counts + Npad;          // Npad (need N+1)
    int*   cursor  = offsets + Npad;         // Npad
    int*   csr     = cursor + Npad;          // E
    float* Wc      = (float*)(csr + E);      // D*D
    float* bc      = Wc + D * D;             // D

    zero_kernel<<<(N4 + 255) / 256, 256, 0, stream>>>((int4*)counts, N4);
    count_kernel<<<(E4 + 255) / 256, 256, 0, stream>>>((const int4*)dst, counts, E4);
    scan4_kernel<<<1, 1024, 0, stream>>>((const int4*)counts, N4, N,
                                         (int4*)offsets, (int4*)cursor, offsets,
                                         proj_W, upd_W, proj_b, Wc, bc);
    fill_kernel<<<(E4 + 255) / 256, 256, 0, stream>>>((const int4*)dst, cursor, csr, E4);

    int blocks_n = (N + 3) / 4;
    node_kernel<<<blocks_n, 256, 0, stream>>>((const float4*)edge_attrs, csr, offsets,
                                              Wc, bc, upd_b, (float*)d_out, N);
}